// Round 1
// baseline (105.328 us; speedup 1.0000x reference)
//
#include <hip/hip_runtime.h>
#include <hip/hip_bf16.h>

#define LRALPHA 0.2f
#define NN 8192
#define FIN 128
#define FOUT 64
#define TI 16
#define TJ 128
#define NT (NN / TJ)

typedef __attribute__((ext_vector_type(4))) float f32x4;
typedef __attribute__((ext_vector_type(8))) short bf16x8;
typedef __attribute__((ext_vector_type(4))) int int4v;

// barrier that does NOT drain vmcnt: LDS writes are made visible (lgkmcnt),
// but prefetched global loads stay in flight across the barrier.
__device__ __forceinline__ void barrier_lgkm() {
  asm volatile("s_waitcnt lgkmcnt(0)\n\ts_barrier" ::: "memory");
}

// ---------------------------------------------------------------------------
// kernel 1: h = inp @ W (fp32), f1 = h@a1, f2 = h@a2, hT[c][row] in bf16
// one wave computes 4 rows; lane = output column
// ---------------------------------------------------------------------------
__global__ __launch_bounds__(256) void prep_kernel(
    const float* __restrict__ inp, const float* __restrict__ Wg,
    const float* __restrict__ ag, float* __restrict__ f1,
    float* __restrict__ f2, unsigned short* __restrict__ hT)
{
  __shared__ alignas(16) float WlT[FOUT][FIN + 4];  // W transposed, padded
  const int t = threadIdx.x;
  for (int i = t; i < FIN * FOUT; i += 256)
    WlT[i & 63][i >> 6] = Wg[i];
  __syncthreads();

  const int lane = t & 63;
  const int row0 = blockIdx.x * 16 + (t >> 6) * 4;

  float h0 = 0.f, h1 = 0.f, h2 = 0.f, h3 = 0.f;
  for (int kk = 0; kk < FIN; kk += 4) {
    f32x4 wv = *(const f32x4*)&WlT[lane][kk];
    f32x4 r0 = *(const f32x4*)&inp[(row0 + 0) * FIN + kk];
    f32x4 r1 = *(const f32x4*)&inp[(row0 + 1) * FIN + kk];
    f32x4 r2 = *(const f32x4*)&inp[(row0 + 2) * FIN + kk];
    f32x4 r3 = *(const f32x4*)&inp[(row0 + 3) * FIN + kk];
    h0 += r0[0]*wv[0] + r0[1]*wv[1] + r0[2]*wv[2] + r0[3]*wv[3];
    h1 += r1[0]*wv[0] + r1[1]*wv[1] + r1[2]*wv[2] + r1[3]*wv[3];
    h2 += r2[0]*wv[0] + r2[1]*wv[1] + r2[2]*wv[2] + r2[3]*wv[3];
    h3 += r3[0]*wv[0] + r3[1]*wv[1] + r3[2]*wv[2] + r3[3]*wv[3];
  }

  const float a1v = ag[lane], a2v = ag[64 + lane];
  float hv[4] = {h0, h1, h2, h3};
#pragma unroll
  for (int rr = 0; rr < 4; ++rr) {
    float c1 = hv[rr] * a1v;
    float c2 = hv[rr] * a2v;
#pragma unroll
    for (int off = 32; off > 0; off >>= 1) {
      c1 += __shfl_xor(c1, off);
      c2 += __shfl_xor(c2, off);
    }
    if (lane == 0) { f1[row0 + rr] = c1; f2[row0 + rr] = c2; }
    __hip_bfloat16 hb = __float2bfloat16(hv[rr]);
    hT[lane * NN + row0 + rr] = __builtin_bit_cast(unsigned short, hb);
  }
}

// ---------------------------------------------------------------------------
// kernel 2: global max of f2 (safe softmax shift for every row)
// ---------------------------------------------------------------------------
__global__ __launch_bounds__(256) void f2max_kernel(
    const float* __restrict__ f2, float* __restrict__ f2m)
{
  const int t = threadIdx.x;
  float m = -1e30f;
  for (int i = t; i < NN / 4; i += 256) {
    f32x4 v = ((const f32x4*)f2)[i];
    m = fmaxf(fmaxf(m, fmaxf(v[0], v[1])), fmaxf(v[2], v[3]));
  }
#pragma unroll
  for (int off = 32; off > 0; off >>= 1)
    m = fmaxf(m, __shfl_xor(m, off));
  __shared__ float ms[4];
  if ((t & 63) == 0) ms[t >> 6] = m;
  __syncthreads();
  if (t == 0)
    f2m[0] = fmaxf(fmaxf(ms[0], ms[1]), fmaxf(ms[2], ms[3]));
}

// ---------------------------------------------------------------------------
// kernel 3: fused masked-softmax attention + BN + ELU
// block = 256 thr (4 waves), TI=16 rows, stream adj in TJ=128 tiles.
//   P-gen: thread (pr = t>>4, pj = (t&15)*8) -> 8 attention weights
//   PV + rowsum via mfma_f32_16x16x32_bf16 (rowsum: B = ones)
// ---------------------------------------------------------------------------
__global__ __launch_bounds__(256, 2) void gat_main(
    const int* __restrict__ adj, const float* __restrict__ f1g,
    const float* __restrict__ f2g, const float* __restrict__ f2m,
    const unsigned short* __restrict__ hTg,
    const float* __restrict__ bng, const float* __restrict__ bnb,
    const float* __restrict__ bnm, const float* __restrict__ bnv,
    float* __restrict__ out)
{
  __shared__ alignas(16) unsigned short Pl[TI][TJ + 8];    // P tile, bf16
  __shared__ alignas(16) unsigned short Hl[FOUT][TJ + 8];  // h^T tile, bf16

  const int t = threadIdx.x;
  const int i0 = blockIdx.x * TI;

  const int pr = t >> 4;          // attention row 0..15
  const int pj = (t & 15) << 3;   // 8 j's per thread

  const float f1v = f1g[i0 + pr];
  const float fmv = f2m[0];
  float mrow = f1v + fmv;
  mrow = mrow > 0.f ? mrow : LRALPHA * mrow;  // upper bound on row max (LR monotone)

  const int hc = t >> 2;          // h^T stage: column 0..63
  const int hj = (t & 3) << 5;    // j offset 0,32,64,96

  const int* adjrow = adj + (i0 + pr) * NN + pj;
  const unsigned short* hrow = hTg + hc * NN + hj;
  const float* f2row = f2g + pj;

  f32x4 acc  = {0.f, 0.f, 0.f, 0.f};   // P @ h
  f32x4 accs = {0.f, 0.f, 0.f, 0.f};   // row sums (same C layout)

  const short ob = (short)0x3F80;      // bf16 1.0
  const bf16x8 onesv = {ob, ob, ob, ob, ob, ob, ob, ob};

  // depth-2 register prefetch: tiles 0 and 1
  int4v aA0 = __builtin_nontemporal_load((const int4v*)adjrow);
  int4v aA1 = __builtin_nontemporal_load((const int4v*)(adjrow + 4));
  f32x4 fA0 = *(const f32x4*)f2row;
  f32x4 fA1 = *(const f32x4*)(f2row + 4);
  int4v hA0 = *(const int4v*)hrow;
  int4v hA1 = *(const int4v*)(hrow + 8);
  int4v hA2 = *(const int4v*)(hrow + 16);
  int4v hA3 = *(const int4v*)(hrow + 24);

  int4v aB0 = __builtin_nontemporal_load((const int4v*)(adjrow + TJ));
  int4v aB1 = __builtin_nontemporal_load((const int4v*)(adjrow + TJ + 4));
  f32x4 fB0 = *(const f32x4*)(f2row + TJ);
  f32x4 fB1 = *(const f32x4*)(f2row + TJ + 4);
  int4v hB0 = *(const int4v*)(hrow + TJ);
  int4v hB1 = *(const int4v*)(hrow + TJ + 8);
  int4v hB2 = *(const int4v*)(hrow + TJ + 16);
  int4v hB3 = *(const int4v*)(hrow + TJ + 24);

  const int l = t & 63;
  const int w = t >> 6;
  const int koff = (l >> 4) << 3;   // fragment: 8 contiguous k per 16-lane group
  const unsigned short* pA = &Pl[l & 15][koff];
  const unsigned short* pB = &Hl[(w << 4) + (l & 15)][koff];

#define TILE_BODY(TT, AJ0, AJ1, F20, F21, H0, H1, H2, H3)                      \
  {                                                                            \
    float x0 = f1v + F20[0]; x0 = (x0 > 0.f ? x0 : LRALPHA * x0) - mrow;       \
    float x1 = f1v + F20[1]; x1 = (x1 > 0.f ? x1 : LRALPHA * x1) - mrow;       \
    float x2 = f1v + F20[2]; x2 = (x2 > 0.f ? x2 : LRALPHA * x2) - mrow;       \
    float x3 = f1v + F20[3]; x3 = (x3 > 0.f ? x3 : LRALPHA * x3) - mrow;       \
    float x4 = f1v + F21[0]; x4 = (x4 > 0.f ? x4 : LRALPHA * x4) - mrow;       \
    float x5 = f1v + F21[1]; x5 = (x5 > 0.f ? x5 : LRALPHA * x5) - mrow;       \
    float x6 = f1v + F21[2]; x6 = (x6 > 0.f ? x6 : LRALPHA * x6) - mrow;       \
    float x7 = f1v + F21[3]; x7 = (x7 > 0.f ? x7 : LRALPHA * x7) - mrow;       \
    float p0 = AJ0[0] > 0 ? __expf(x0) : 0.f;                                  \
    float p1 = AJ0[1] > 0 ? __expf(x1) : 0.f;                                  \
    float p2 = AJ0[2] > 0 ? __expf(x2) : 0.f;                                  \
    float p3 = AJ0[3] > 0 ? __expf(x3) : 0.f;                                  \
    float p4 = AJ1[0] > 0 ? __expf(x4) : 0.f;                                  \
    float p5 = AJ1[1] > 0 ? __expf(x5) : 0.f;                                  \
    float p6 = AJ1[2] > 0 ? __expf(x6) : 0.f;                                  \
    float p7 = AJ1[3] > 0 ? __expf(x7) : 0.f;                                  \
    unsigned short u0 = __builtin_bit_cast(unsigned short, __float2bfloat16(p0)); \
    unsigned short u1 = __builtin_bit_cast(unsigned short, __float2bfloat16(p1)); \
    unsigned short u2 = __builtin_bit_cast(unsigned short, __float2bfloat16(p2)); \
    unsigned short u3 = __builtin_bit_cast(unsigned short, __float2bfloat16(p3)); \
    unsigned short u4 = __builtin_bit_cast(unsigned short, __float2bfloat16(p4)); \
    unsigned short u5 = __builtin_bit_cast(unsigned short, __float2bfloat16(p5)); \
    unsigned short u6 = __builtin_bit_cast(unsigned short, __float2bfloat16(p6)); \
    unsigned short u7 = __builtin_bit_cast(unsigned short, __float2bfloat16(p7)); \
    int4v pw = {(int)u0 | ((int)u1 << 16), (int)u2 | ((int)u3 << 16),          \
                (int)u4 | ((int)u5 << 16), (int)u6 | ((int)u7 << 16)};         \
    *(int4v*)&Pl[pr][pj] = pw;                                                 \
    *(int4v*)&Hl[hc][hj]      = H0;                                            \
    *(int4v*)&Hl[hc][hj + 8]  = H1;                                            \
    *(int4v*)&Hl[hc][hj + 16] = H2;                                            \
    *(int4v*)&Hl[hc][hj + 24] = H3;                                            \
    if ((TT) + 2 < NT) {                                                       \
      AJ0 = __builtin_nontemporal_load((const int4v*)(adjrow + ((TT)+2)*TJ));      \
      AJ1 = __builtin_nontemporal_load((const int4v*)(adjrow + ((TT)+2)*TJ + 4));  \
      F20 = *(const f32x4*)(f2row + ((TT)+2)*TJ);                              \
      F21 = *(const f32x4*)(f2row + ((TT)+2)*TJ + 4);                          \
      H0 = *(const int4v*)(hrow + ((TT)+2)*TJ);                                \
      H1 = *(const int4v*)(hrow + ((TT)+2)*TJ + 8);                            \
      H2 = *(const int4v*)(hrow + ((TT)+2)*TJ + 16);                           \
      H3 = *(const int4v*)(hrow + ((TT)+2)*TJ + 24);                           \
    }                                                                          \
    barrier_lgkm();                                                            \
    {                                                                          \
      bf16x8 av, bv;                                                           \
      av = *(const bf16x8*)(pA);       bv = *(const bf16x8*)(pB);              \
      acc  = __builtin_amdgcn_mfma_f32_16x16x32_bf16(av, bv, acc, 0, 0, 0);    \
      accs = __builtin_amdgcn_mfma_f32_16x16x32_bf16(av, onesv, accs, 0, 0, 0);\
      av = *(const bf16x8*)(pA + 32);  bv = *(const bf16x8*)(pB + 32);         \
      acc  = __builtin_amdgcn_mfma_f32_16x16x32_bf16(av, bv, acc, 0, 0, 0);    \
      accs = __builtin_amdgcn_mfma_f32_16x16x32_bf16(av, onesv, accs, 0, 0, 0);\
      av = *(const bf16x8*)(pA + 64);  bv = *(const bf16x8*)(pB + 64);         \
      acc  = __builtin_amdgcn_mfma_f32_16x16x32_bf16(av, bv, acc, 0, 0, 0);    \
      accs = __builtin_amdgcn_mfma_f32_16x16x32_bf16(av, onesv, accs, 0, 0, 0);\
      av = *(const bf16x8*)(pA + 96);  bv = *(const bf16x8*)(pB + 96);         \
      acc  = __builtin_amdgcn_mfma_f32_16x16x32_bf16(av, bv, acc, 0, 0, 0);    \
      accs = __builtin_amdgcn_mfma_f32_16x16x32_bf16(av, onesv, accs, 0, 0, 0);\
    }                                                                          \
    barrier_lgkm();                                                            \
  }

  for (int tt = 0; tt < NT; tt += 2) {
    TILE_BODY(tt,     aA0, aA1, fA0, fA1, hA0, hA1, hA2, hA3);
    TILE_BODY(tt + 1, aB0, aB1, fB0, fB1, hB0, hB1, hB2, hB3);
  }
#undef TILE_BODY

  // epilogue: divide by row sum, batch norm, ELU
  const int gcol = (w << 4) + (l & 15);
  const float inv_sd = rsqrtf(bnv[gcol] + 1e-5f);
  const float ga = bng[gcol], be = bnb[gcol], mu = bnm[gcol];
  const int rbase = (l >> 4) << 2;
#pragma unroll
  for (int q = 0; q < 4; ++q) {
    float v = acc[q] / accs[q];
    v = (v - mu) * inv_sd * ga + be;
    v = v > 0.f ? v : expm1f(v);
    out[(i0 + rbase + q) * FOUT + gcol] = v;
  }
}

// ---------------------------------------------------------------------------
extern "C" void kernel_launch(void* const* d_in, const int* in_sizes, int n_in,
                              void* d_out, int out_size, void* d_ws, size_t ws_size,
                              hipStream_t stream)
{
  (void)in_sizes; (void)n_in; (void)out_size; (void)ws_size;
  const float* inp = (const float*)d_in[0];
  const int*   adj = (const int*)d_in[1];
  const float* Wg  = (const float*)d_in[2];
  const float* ag  = (const float*)d_in[3];
  const float* bng = (const float*)d_in[4];
  const float* bnb = (const float*)d_in[5];
  const float* bnm = (const float*)d_in[6];
  const float* bnv = (const float*)d_in[7];
  float* out = (float*)d_out;

  char* ws = (char*)d_ws;
  unsigned short* hT = (unsigned short*)ws;                 // 64*8192*2 = 1 MiB
  float* f1 = (float*)(ws + (size_t)NN * FOUT * 2);         // 32 KiB
  float* f2 = f1 + NN;                                      // 32 KiB
  float* f2m = f2 + NN;                                     // 4 B

  prep_kernel<<<NN / 16, 256, 0, stream>>>(inp, Wg, ag, f1, f2, hT);
  f2max_kernel<<<1, 256, 0, stream>>>(f2, f2m);
  gat_main<<<NN / TI, 256, 0, stream>>>(adj, f1, f2, f2m, hT,
                                        bng, bnb, bnm, bnv, out);
}

// Round 2
// 104.527 us; speedup vs baseline: 1.0077x; 1.0077x over previous
//
#include <hip/hip_runtime.h>
#include <hip/hip_bf16.h>

#define LRALPHA 0.2f
#define NN 8192
#define FIN 128
#define FOUT 64
#define TI 16
#define TJ 128
#define NT (NN / TJ)

typedef __attribute__((ext_vector_type(4))) float f32x4;
typedef __attribute__((ext_vector_type(8))) short bf16x8;
typedef __attribute__((ext_vector_type(4))) int int4v;
typedef __attribute__((ext_vector_type(2))) int int2v;

// barrier that does NOT drain vmcnt: LDS writes are made visible (lgkmcnt),
// but prefetched global loads stay in flight across the barrier.
__device__ __forceinline__ void barrier_lgkm() {
  asm volatile("s_waitcnt lgkmcnt(0)\n\ts_barrier" ::: "memory");
}

// ---------------------------------------------------------------------------
// kernel 1: h = inp @ W (fp32), f1 = h@a1, f2 = h@a2, hT[c][row] in bf16
// ---------------------------------------------------------------------------
__global__ __launch_bounds__(256) void prep_kernel(
    const float* __restrict__ inp, const float* __restrict__ Wg,
    const float* __restrict__ ag, float* __restrict__ f1,
    float* __restrict__ f2, unsigned short* __restrict__ hT)
{
  __shared__ alignas(16) float WlT[FOUT][FIN + 4];  // W transposed, padded
  const int t = threadIdx.x;
  for (int i = t; i < FIN * FOUT; i += 256)
    WlT[i & 63][i >> 6] = Wg[i];
  __syncthreads();

  const int lane = t & 63;
  const int row0 = blockIdx.x * 16 + (t >> 6) * 4;

  float h0 = 0.f, h1 = 0.f, h2 = 0.f, h3 = 0.f;
  for (int kk = 0; kk < FIN; kk += 4) {
    f32x4 wv = *(const f32x4*)&WlT[lane][kk];
    f32x4 r0 = *(const f32x4*)&inp[(row0 + 0) * FIN + kk];
    f32x4 r1 = *(const f32x4*)&inp[(row0 + 1) * FIN + kk];
    f32x4 r2 = *(const f32x4*)&inp[(row0 + 2) * FIN + kk];
    f32x4 r3 = *(const f32x4*)&inp[(row0 + 3) * FIN + kk];
    h0 += r0[0]*wv[0] + r0[1]*wv[1] + r0[2]*wv[2] + r0[3]*wv[3];
    h1 += r1[0]*wv[0] + r1[1]*wv[1] + r1[2]*wv[2] + r1[3]*wv[3];
    h2 += r2[0]*wv[0] + r2[1]*wv[1] + r2[2]*wv[2] + r2[3]*wv[3];
    h3 += r3[0]*wv[0] + r3[1]*wv[1] + r3[2]*wv[2] + r3[3]*wv[3];
  }

  const float a1v = ag[lane], a2v = ag[64 + lane];
  float hv[4] = {h0, h1, h2, h3};
#pragma unroll
  for (int rr = 0; rr < 4; ++rr) {
    float c1 = hv[rr] * a1v;
    float c2 = hv[rr] * a2v;
#pragma unroll
    for (int off = 32; off > 0; off >>= 1) {
      c1 += __shfl_xor(c1, off);
      c2 += __shfl_xor(c2, off);
    }
    if (lane == 0) { f1[row0 + rr] = c1; f2[row0 + rr] = c2; }
    __hip_bfloat16 hb = __float2bfloat16(hv[rr]);
    hT[lane * NN + row0 + rr] = __builtin_bit_cast(unsigned short, hb);
  }
}

// ---------------------------------------------------------------------------
// kernel 2: global max of f2 (safe softmax shift for every row)
// ---------------------------------------------------------------------------
__global__ __launch_bounds__(256) void f2max_kernel(
    const float* __restrict__ f2, float* __restrict__ f2m)
{
  const int t = threadIdx.x;
  float m = -1e30f;
  for (int i = t; i < NN / 4; i += 256) {
    f32x4 v = ((const f32x4*)f2)[i];
    m = fmaxf(fmaxf(m, fmaxf(v[0], v[1])), fmaxf(v[2], v[3]));
  }
#pragma unroll
  for (int off = 32; off > 0; off >>= 1)
    m = fmaxf(m, __shfl_xor(m, off));
  __shared__ float ms[4];
  if ((t & 63) == 0) ms[t >> 6] = m;
  __syncthreads();
  if (t == 0)
    f2m[0] = fmaxf(fmaxf(ms[0], ms[1]), fmaxf(ms[2], ms[3]));
}

// ---------------------------------------------------------------------------
// kernel 3: fused masked-softmax attention + BN + ELU
// block = 256 thr (4 waves), TI=16 rows, TJ=128 j-tiles, depth-4 register
// prefetch on the adj/f2/hT streams; PV via mfma_f32_16x16x32_bf16;
// row sums in fp32 VALU (shfl reduce).
// ---------------------------------------------------------------------------
__global__ __launch_bounds__(256, 2) void gat_main(
    const int* __restrict__ adj, const float* __restrict__ f1g,
    const float* __restrict__ f2g, const float* __restrict__ f2m,
    const unsigned short* __restrict__ hTg,
    const float* __restrict__ bng, const float* __restrict__ bnb,
    const float* __restrict__ bnm, const float* __restrict__ bnv,
    float* __restrict__ out)
{
  __shared__ alignas(16) unsigned short Pl[TI][TJ + 8];    // P tile, bf16
  __shared__ alignas(16) unsigned short Hl[FOUT][TJ + 8];  // h^T tile, bf16
  __shared__ float rs_lds[TI];                             // row sums

  const int t = threadIdx.x;
  const int i0 = blockIdx.x * TI;

  const int pr = t >> 4;          // attention row 0..15
  const int c  = t & 15;          // j-chunk index: j = c*4 and 64+c*4

  const float f1v = f1g[i0 + pr];
  const float fmv = f2m[0];
  float mrow = f1v + fmv;
  mrow = mrow > 0.f ? mrow : LRALPHA * mrow;  // upper bound on row max

  const int hc = t >> 2;          // h^T stage: column 0..63
  const int hj = (t & 3) << 5;    // j offset 0,32,64,96

  const int* adjrow = adj + (i0 + pr) * NN + c * 4;
  const unsigned short* hrow = hTg + hc * NN + hj;
  const float* f2row = f2g + c * 4;

  f32x4 acc = {0.f, 0.f, 0.f, 0.f};   // P @ h
  float rs = 0.f;                     // fp32 row-sum partial

  const int l = t & 63;
  const int w = t >> 6;
  const int koff = (l >> 4) << 3;
  const unsigned short* pA = &Pl[l & 15][koff];
  const unsigned short* pB = &Hl[(w << 4) + (l & 15)][koff];

  // 4 prefetch buffers
  int4v aA0,aA1,aB0,aB1,aC0,aC1,aD0,aD1;
  f32x4 fA0,fA1,fB0,fB1,fC0,fC1,fD0,fD1;
  int4v hA0,hA1,hA2,hA3,hB0,hB1,hB2,hB3;
  int4v hC0,hC1,hC2,hC3,hD0,hD1,hD2,hD3;

#define PREF(A0,A1,F0,F1,H0,H1,H2,H3,T)                                        \
  {                                                                            \
    const int _tn = (T) < NT ? (T) : (NT - 1);                                 \
    A0 = __builtin_nontemporal_load((const int4v*)(adjrow + _tn * TJ));        \
    A1 = __builtin_nontemporal_load((const int4v*)(adjrow + _tn * TJ + 64));   \
    F0 = *(const f32x4*)(f2row + _tn * TJ);                                    \
    F1 = *(const f32x4*)(f2row + _tn * TJ + 64);                               \
    H0 = *(const int4v*)(hrow + _tn * TJ);                                     \
    H1 = *(const int4v*)(hrow + _tn * TJ + 8);                                 \
    H2 = *(const int4v*)(hrow + _tn * TJ + 16);                                \
    H3 = *(const int4v*)(hrow + _tn * TJ + 24);                                \
  }

  // prologue: fill all 4 buffers (tiles 0..3)
  PREF(aA0,aA1,fA0,fA1,hA0,hA1,hA2,hA3, 0);
  PREF(aB0,aB1,fB0,fB1,hB0,hB1,hB2,hB3, 1);
  PREF(aC0,aC1,fC0,fC1,hC0,hC1,hC2,hC3, 2);
  PREF(aD0,aD1,fD0,fD1,hD0,hD1,hD2,hD3, 3);

#define TILE_BODY(A0,A1,F0,F1,H0,H1,H2,H3,T)                                   \
  {                                                                            \
    float x0 = f1v + F0[0]; x0 = fmaxf(x0, LRALPHA * x0) - mrow;               \
    float x1 = f1v + F0[1]; x1 = fmaxf(x1, LRALPHA * x1) - mrow;               \
    float x2 = f1v + F0[2]; x2 = fmaxf(x2, LRALPHA * x2) - mrow;               \
    float x3 = f1v + F0[3]; x3 = fmaxf(x3, LRALPHA * x3) - mrow;               \
    float x4 = f1v + F1[0]; x4 = fmaxf(x4, LRALPHA * x4) - mrow;               \
    float x5 = f1v + F1[1]; x5 = fmaxf(x5, LRALPHA * x5) - mrow;               \
    float x6 = f1v + F1[2]; x6 = fmaxf(x6, LRALPHA * x6) - mrow;               \
    float x7 = f1v + F1[3]; x7 = fmaxf(x7, LRALPHA * x7) - mrow;               \
    float p0 = A0[0] > 0 ? __expf(x0) : 0.f;                                   \
    float p1 = A0[1] > 0 ? __expf(x1) : 0.f;                                   \
    float p2 = A0[2] > 0 ? __expf(x2) : 0.f;                                   \
    float p3 = A0[3] > 0 ? __expf(x3) : 0.f;                                   \
    float p4 = A1[0] > 0 ? __expf(x4) : 0.f;                                   \
    float p5 = A1[1] > 0 ? __expf(x5) : 0.f;                                   \
    float p6 = A1[2] > 0 ? __expf(x6) : 0.f;                                   \
    float p7 = A1[3] > 0 ? __expf(x7) : 0.f;                                   \
    rs += ((p0 + p1) + (p2 + p3)) + ((p4 + p5) + (p6 + p7));                   \
    unsigned short u0 = __builtin_bit_cast(unsigned short, __float2bfloat16(p0)); \
    unsigned short u1 = __builtin_bit_cast(unsigned short, __float2bfloat16(p1)); \
    unsigned short u2 = __builtin_bit_cast(unsigned short, __float2bfloat16(p2)); \
    unsigned short u3 = __builtin_bit_cast(unsigned short, __float2bfloat16(p3)); \
    unsigned short u4 = __builtin_bit_cast(unsigned short, __float2bfloat16(p4)); \
    unsigned short u5 = __builtin_bit_cast(unsigned short, __float2bfloat16(p5)); \
    unsigned short u6 = __builtin_bit_cast(unsigned short, __float2bfloat16(p6)); \
    unsigned short u7 = __builtin_bit_cast(unsigned short, __float2bfloat16(p7)); \
    int2v pw0 = {(int)u0 | ((int)u1 << 16), (int)u2 | ((int)u3 << 16)};        \
    int2v pw1 = {(int)u4 | ((int)u5 << 16), (int)u6 | ((int)u7 << 16)};        \
    *(int2v*)&Pl[pr][c * 4]      = pw0;                                        \
    *(int2v*)&Pl[pr][64 + c * 4] = pw1;                                        \
    *(int4v*)&Hl[hc][hj]      = H0;                                            \
    *(int4v*)&Hl[hc][hj + 8]  = H1;                                            \
    *(int4v*)&Hl[hc][hj + 16] = H2;                                            \
    *(int4v*)&Hl[hc][hj + 24] = H3;                                            \
    PREF(A0,A1,F0,F1,H0,H1,H2,H3, (T) + 4);                                    \
    barrier_lgkm();                                                            \
    {                                                                          \
      bf16x8 av, bv;                                                           \
      av = *(const bf16x8*)(pA);       bv = *(const bf16x8*)(pB);              \
      acc = __builtin_amdgcn_mfma_f32_16x16x32_bf16(av, bv, acc, 0, 0, 0);     \
      av = *(const bf16x8*)(pA + 32);  bv = *(const bf16x8*)(pB + 32);         \
      acc = __builtin_amdgcn_mfma_f32_16x16x32_bf16(av, bv, acc, 0, 0, 0);     \
      av = *(const bf16x8*)(pA + 64);  bv = *(const bf16x8*)(pB + 64);         \
      acc = __builtin_amdgcn_mfma_f32_16x16x32_bf16(av, bv, acc, 0, 0, 0);     \
      av = *(const bf16x8*)(pA + 96);  bv = *(const bf16x8*)(pB + 96);         \
      acc = __builtin_amdgcn_mfma_f32_16x16x32_bf16(av, bv, acc, 0, 0, 0);     \
    }                                                                          \
    barrier_lgkm();                                                            \
  }

  for (int tt = 0; tt < NT; tt += 4) {
    TILE_BODY(aA0,aA1,fA0,fA1,hA0,hA1,hA2,hA3, tt);
    TILE_BODY(aB0,aB1,fB0,fB1,hB0,hB1,hB2,hB3, tt + 1);
    TILE_BODY(aC0,aC1,fC0,fC1,hC0,hC1,hC2,hC3, tt + 2);
    TILE_BODY(aD0,aD1,fD0,fD1,hD0,hD1,hD2,hD3, tt + 3);
  }
#undef TILE_BODY
#undef PREF

  // row-sum: reduce rs across the 16 c-threads of each row (lanes c=0..15
  // of a 16-lane group, so width-16 xor shuffles stay in-group)
  rs += __shfl_xor(rs, 1);
  rs += __shfl_xor(rs, 2);
  rs += __shfl_xor(rs, 4);
  rs += __shfl_xor(rs, 8);
  if (c == 0) rs_lds[pr] = rs;
  __syncthreads();

  // epilogue: divide by row sum, batch norm, ELU
  const int gcol = (w << 4) + (l & 15);
  const float inv_sd = rsqrtf(bnv[gcol] + 1e-5f);
  const float ga = bng[gcol], be = bnb[gcol], mu = bnm[gcol];
  const int rbase = (l >> 4) << 2;
#pragma unroll
  for (int q = 0; q < 4; ++q) {
    float v = acc[q] / rs_lds[rbase + q];
    v = (v - mu) * inv_sd * ga + be;
    v = v > 0.f ? v : expm1f(v);
    out[(i0 + rbase + q) * FOUT + gcol] = v;
  }
}

// ---------------------------------------------------------------------------
extern "C" void kernel_launch(void* const* d_in, const int* in_sizes, int n_in,
                              void* d_out, int out_size, void* d_ws, size_t ws_size,
                              hipStream_t stream)
{
  (void)in_sizes; (void)n_in; (void)out_size; (void)ws_size;
  const float* inp = (const float*)d_in[0];
  const int*   adj = (const int*)d_in[1];
  const float* Wg  = (const float*)d_in[2];
  const float* ag  = (const float*)d_in[3];
  const float* bng = (const float*)d_in[4];
  const float* bnb = (const float*)d_in[5];
  const float* bnm = (const float*)d_in[6];
  const float* bnv = (const float*)d_in[7];
  float* out = (float*)d_out;

  char* ws = (char*)d_ws;
  unsigned short* hT = (unsigned short*)ws;                 // 64*8192*2 = 1 MiB
  float* f1 = (float*)(ws + (size_t)NN * FOUT * 2);         // 32 KiB
  float* f2 = f1 + NN;                                      // 32 KiB
  float* f2m = f2 + NN;                                     // 4 B

  prep_kernel<<<NN / 16, 256, 0, stream>>>(inp, Wg, ag, f1, f2, hT);
  f2max_kernel<<<1, 256, 0, stream>>>(f2, f2m);
  gat_main<<<NN / TI, 256, 0, stream>>>(adj, f1, f2, f2m, hT,
                                        bng, bnb, bnm, bnv, out);
}